// Round 8
// baseline (538.791 us; speedup 1.0000x reference)
//
#include <hip/hip_runtime.h>
#include <hip/hip_bf16.h>
#include <math.h>

typedef __bf16 bf16_t;
typedef __bf16 bf16x8 __attribute__((ext_vector_type(8)));
typedef __bf16 bf16x4 __attribute__((ext_vector_type(4)));
typedef float f32x4 __attribute__((ext_vector_type(4)));
typedef float f32x16 __attribute__((ext_vector_type(16)));
typedef unsigned int u32;

#define MFMA16 __builtin_amdgcn_mfma_f32_16x16x32_bf16
#define MFMA32 __builtin_amdgcn_mfma_f32_32x32x16_bf16

static __device__ __forceinline__ u32 pkbf(float a, float b) {
  union { bf16_t h[2]; u32 u; } z;
  z.h[0] = (bf16_t)a; z.h[1] = (bf16_t)b;
  return z.u;
}

// async global->LDS, 16B per lane, dest = wave-uniform base + lane*16
static __device__ __forceinline__ void gload16(const bf16_t* g, bf16_t* l) {
  __builtin_amdgcn_global_load_lds(
      (const __attribute__((address_space(1))) void*)g,
      (__attribute__((address_space(3))) void*)l, 16, 0, 0);
}

// ---------------- x: f32 -> bf16 ----------------
__global__ void k_f32_to_bf16(const float* __restrict__ in, bf16_t* __restrict__ out, long n) {
  long i = ((long)blockIdx.x * blockDim.x + threadIdx.x) * 4;
  long stride = (long)gridDim.x * blockDim.x * 4;
  for (; i < n; i += stride) {
    const float4 v = *(const float4*)(in + i);
    bf16x4 o; o[0] = (bf16_t)v.x; o[1] = (bf16_t)v.y; o[2] = (bf16_t)v.z; o[3] = (bf16_t)v.w;
    *(bf16x4*)(out + i) = o;
  }
}

// ------------- W (KxN f32) -> WT (NxK bf16), LDS tile transpose -------------
__global__ void k_transpose_bf16(const float* __restrict__ W, bf16_t* __restrict__ WT,
                                 int K, int N) {
  __shared__ float tile[32][33];
  int n0 = blockIdx.x * 32, k0 = blockIdx.y * 32;
  int tx = threadIdx.x & 31, ty = threadIdx.x >> 5;
#pragma unroll
  for (int i = 0; i < 4; i++)
    tile[ty + i * 8][tx] = W[(size_t)(k0 + ty + i * 8) * N + n0 + tx];
  __syncthreads();
#pragma unroll
  for (int i = 0; i < 4; i++) {
    int n = ty + i * 8;
    WT[(size_t)(n0 + n) * K + k0 + tx] = (bf16_t)tile[tx][n];
  }
}

// ------------- V slab of qkv -> VT [b*512 + kvh*128 + d][2048 t] -------------
__global__ void k_build_vt(const bf16_t* __restrict__ qkv, bf16_t* __restrict__ VT) {
  __shared__ bf16_t tile[32][33];
  int t0 = blockIdx.x * 32, c0 = blockIdx.y * 32, b = blockIdx.z;
  int tx = threadIdx.x & 31, ty = threadIdx.x >> 5;
  const bf16_t* src = qkv + (size_t)b * 2048 * 3072 + 2560;
#pragma unroll
  for (int i = 0; i < 4; i++)
    tile[ty + i * 8][tx] = src[(size_t)(t0 + ty + i * 8) * 3072 + c0 + tx];
  __syncthreads();
  bf16_t* dst = VT + (size_t)b * 512 * 2048;
#pragma unroll
  for (int i = 0; i < 4; i++)
    dst[(size_t)(c0 + ty + i * 8) * 2048 + t0 + tx] = tile[tx][ty + i * 8];
}

// ---------------- RoPE on q,k columns of qkv (in place) ----------------
__global__ void k_rope(bf16_t* __restrict__ qkv) {
  int idx = blockIdx.x * blockDim.x + threadIdx.x;
  if (idx >= 8192 * 1280) return;
  int r = idx / 1280, p = idx - r * 1280;
  int t = r & 2047;
  int i = p & 63;
  float theta = exp2f(-(float)i * 0.41524101186092029f);
  float f = (float)t * theta;
  float s, c;
  sincosf(f, &s, &c);
  bf16_t* a = qkv + (size_t)r * 3072 + p * 2;
  float e = (float)a[0], o = (float)a[1];
  a[0] = (bf16_t)(e * c - o * s);
  a[1] = (bf16_t)(e * s + o * c);
}

// ---------------- GEMM v2: 256x256 tile, 8-wave, 4-phase/K-tile pipeline ----
template <bool F32OUT>
__global__ __launch_bounds__(512, 2) void k_gemm_bt(
    const bf16_t* __restrict__ A, const bf16_t* __restrict__ BT,
    bf16_t* __restrict__ Cb, float* __restrict__ Cf,
    const float* __restrict__ bias, int M, int N, int K, int nwg) {
  __shared__ bf16_t smem[65536];  // [2 buf][A 16384 | B 16384]
  const int nbn = N >> 8;
  int orig = (int)blockIdx.x;
  int swz = (orig & 7) * (nwg >> 3) + (orig >> 3);  // bijective, nwg%8==0
  int bm = swz / nbn, bn = swz % nbn;
  const int tid = threadIdx.x;
  const int lane = tid & 63, wid = tid >> 6;
  const int wm = (wid >> 2) << 7;  // 0 / 128
  const int wn = (wid & 3) << 6;   // 0 / 64 / 128 / 192
  const int lr = lane & 15, lq = lane >> 4;
  f32x4 acc[8][4] = {};

  const int rl = tid >> 3;               // row within 64-row chunk
  const int ss = (tid & 7) ^ (rl & 7);   // pre-swizzled source 16B-slot
  const bf16_t* gA = A + (size_t)(bm * 256 + rl) * K + ss * 8;
  const bf16_t* gB = BT + (size_t)(bn * 256 + rl) * K + ss * 8;
  const int lo = wid * 512;  // wave-uniform LDS offset within issue chunk

  const int nt = K >> 6;
  {  // prologue: stage tile 0, full drain once
    bf16_t* sA0 = smem;
    bf16_t* sB0 = smem + 16384;
#pragma unroll
    for (int i = 0; i < 4; i++) {
      gload16(gA + (size_t)i * 64 * K, sA0 + i * 4096 + lo);
      gload16(gB + (size_t)i * 64 * K, sB0 + i * 4096 + lo);
    }
  }
  asm volatile("s_waitcnt vmcnt(0)" ::: "memory");
  __syncthreads();

  for (int t = 0; t < nt; ++t) {
    bf16_t* sAc = smem + (t & 1) * 32768;
    bf16_t* sBc = sAc + 16384;
    bf16_t* sAn = smem + ((t & 1) ^ 1) * 32768;
    bf16_t* sBn = sAn + 16384;
    const int k1 = (t + 1) << 6;
    bf16x8 breg[4][2];
    // ---- phase 0: read all B frags + A frags m0,m1; issue next tile ----
#pragma unroll
    for (int n = 0; n < 4; n++)
#pragma unroll
      for (int kk = 0; kk < 2; kk++) {
        int R = wn + n * 16 + lr;
        int u = (kk * 4 + lq) ^ (R & 7);
        breg[n][kk] = *(const bf16x8*)&sBc[R * 64 + u * 8];
      }
    {
      bf16x8 areg[2][2];
#pragma unroll
      for (int ml = 0; ml < 2; ml++)
#pragma unroll
        for (int kk = 0; kk < 2; kk++) {
          int R = wm + ml * 16 + lr;
          int u = (kk * 4 + lq) ^ (R & 7);
          areg[ml][kk] = *(const bf16x8*)&sAc[R * 64 + u * 8];
        }
      if (t + 1 < nt) {
#pragma unroll
        for (int i = 0; i < 4; i++) {
          gload16(gA + (size_t)i * 64 * K + k1, sAn + i * 4096 + lo);
          gload16(gB + (size_t)i * 64 * K + k1, sBn + i * 4096 + lo);
        }
      }
      __builtin_amdgcn_s_barrier();
      asm volatile("s_waitcnt lgkmcnt(0)" ::: "memory");
      __builtin_amdgcn_sched_barrier(0);
      __builtin_amdgcn_s_setprio(1);
#pragma unroll
      for (int ml = 0; ml < 2; ml++)
#pragma unroll
        for (int n = 0; n < 4; n++)
#pragma unroll
          for (int kk = 0; kk < 2; kk++)
            acc[ml][n] = MFMA16(areg[ml][kk], breg[n][kk], acc[ml][n], 0, 0, 0);
      __builtin_amdgcn_s_setprio(0);
      __builtin_amdgcn_s_barrier();
    }
    // ---- phases 1..3: A frags m=2p..2p+1 ----
#pragma unroll
    for (int p = 1; p < 4; p++) {
      bf16x8 areg[2][2];
#pragma unroll
      for (int ml = 0; ml < 2; ml++)
#pragma unroll
        for (int kk = 0; kk < 2; kk++) {
          int R = wm + (2 * p + ml) * 16 + lr;
          int u = (kk * 4 + lq) ^ (R & 7);
          areg[ml][kk] = *(const bf16x8*)&sAc[R * 64 + u * 8];
        }
      __builtin_amdgcn_s_barrier();
      asm volatile("s_waitcnt lgkmcnt(0)" ::: "memory");
      __builtin_amdgcn_sched_barrier(0);
      __builtin_amdgcn_s_setprio(1);
#pragma unroll
      for (int ml = 0; ml < 2; ml++)
#pragma unroll
        for (int n = 0; n < 4; n++)
#pragma unroll
          for (int kk = 0; kk < 2; kk++)
            acc[2 * p + ml][n] = MFMA16(areg[ml][kk], breg[n][kk], acc[2 * p + ml][n], 0, 0, 0);
      __builtin_amdgcn_s_setprio(0);
      if (p == 3) {
        asm volatile("s_waitcnt vmcnt(0)" ::: "memory");
        __builtin_amdgcn_sched_barrier(0);
      }
      __builtin_amdgcn_s_barrier();
    }
  }
  // ---- epilogue ----
#pragma unroll
  for (int m = 0; m < 8; m++) {
    int row0 = bm * 256 + wm + m * 16 + lq * 4;
#pragma unroll
    for (int n = 0; n < 4; n++) {
      int col = bn * 256 + wn + n * 16 + lr;
#pragma unroll
      for (int r = 0; r < 4; r++) {
        if constexpr (F32OUT)
          Cf[(size_t)(row0 + r) * N + col] = acc[m][n][r] + bias[col];
        else
          Cb[(size_t)(row0 + r) * N + col] = (bf16_t)acc[m][n][r];
      }
    }
  }
}

// ---------------- Flash attention v7 (causal, GQA) ----------------
// 4 waves x 64 q-rows (2 groups of 32), block = 256 q-rows, grid 512.
// K/V staged via global_load_lds (pre-swizzled source), double-buffered.
// One vmcnt(0)+barrier per tile. V fragments shared by both q-groups.
__global__ __launch_bounds__(256, 2) void k_attn(const bf16_t* __restrict__ qkv,
                                                 const bf16_t* __restrict__ VT,
                                                 bf16_t* __restrict__ out) {
  __shared__ bf16_t sK[2][64 * 128];   // [k][d-slot^]; slot sl holds granule sl^(row&7)
  __shared__ bf16_t sV[2][128 * 64];   // [d][k-slot^]
  int bid = blockIdx.x;
  int gq = bid >> 6;
  // pair-balanced qt permutation {7,5,6,4,0,2,1,3} (pairs g,g+4 sum to 7)
  const u32 permbits = (7u) | (5u << 3) | (6u << 6) | (4u << 9) |
                       (0u << 12) | (2u << 15) | (1u << 18) | (3u << 21);
  int qt = (permbits >> (gq * 3)) & 7;
  int bh = bid & 63;
  int h = bh & 15, b = bh >> 4;
  int kvh = h >> 2;
  const size_t RS = 3072;
  const bf16_t* Qb = qkv + (size_t)b * 2048 * RS + h * 128;
  const bf16_t* Kb = qkv + (size_t)b * 2048 * RS + 2048 + kvh * 128;
  const bf16_t* Vt = VT + (size_t)(b * 4 + kvh) * 128 * 2048;
  int tid = threadIdx.x, lane = tid & 63, wid = tid >> 6;
  int l31 = lane & 31, hi = lane >> 5;
  int qw = qt * 256 + wid * 64;  // q-groups at qw and qw+32

  // Q fragments, both groups (B operand: row=l31, k = dc*16 + hi*8 + j)
  bf16x8 qf0[8], qf1[8];
  {
    const bf16_t* q0r = Qb + (size_t)(qw + l31) * RS + hi * 8;
    const bf16_t* q1r = Qb + (size_t)(qw + 32 + l31) * RS + hi * 8;
#pragma unroll
    for (int dc = 0; dc < 8; dc++) {
      qf0[dc] = *(const bf16x8*)(q0r + dc * 16);
      qf1[dc] = *(const bf16x8*)(q1r + dc * 16);
    }
  }

  // pre-swizzled staging source addresses (rule 21: source perm == read perm)
  const bf16_t* Kst = Kb + (size_t)(tid >> 4) * RS + ((tid & 15) ^ ((tid >> 4) & 7)) * 8;
  const bf16_t* Vst = Vt + (size_t)(tid >> 3) * 2048 + ((tid & 7) ^ ((tid >> 3) & 7)) * 8;

  f32x16 oT[8] = {};  // [0..3] group0, [4..7] group1
  float m0 = -INFINITY, l0 = 0.f, m1 = -INFINITY, l1 = 0.f;
  const float SC = 0.08838834764831845f * 1.4426950408889634f;  // D^-0.5 * log2(e)

  int ntiles = qt * 4 + 4;
  // prologue: stage tile 0 into buf 0
#pragma unroll
  for (int i = 0; i < 4; i++)
    gload16(Kst + (size_t)(i * 16) * RS, &sK[0][i * 2048 + wid * 512]);
#pragma unroll
  for (int i = 0; i < 4; i++)
    gload16(Vst + (size_t)(i * 32) * 2048, &sV[0][i * 2048 + wid * 512]);

  for (int kt = 0; kt < ntiles; kt++) {
    int k0 = kt << 6;
    int cur = kt & 1;
    asm volatile("s_waitcnt vmcnt(0)" ::: "memory");
    __builtin_amdgcn_s_barrier();
    __builtin_amdgcn_sched_barrier(0);
    if (kt + 1 < ntiles) {
      int k1 = k0 + 64;
#pragma unroll
      for (int i = 0; i < 4; i++)
        gload16(Kst + (size_t)(k1 + i * 16) * RS, &sK[cur ^ 1][i * 2048 + wid * 512]);
#pragma unroll
      for (int i = 0; i < 4; i++)
        gload16(Vst + (size_t)(i * 32) * 2048 + k1, &sV[cur ^ 1][i * 2048 + wid * 512]);
    }
    if (k0 > qw) continue;  // wave-uniform causal skip (barrier already passed)
    bool diag = (k0 == qw);
    const char* sKc = (const char*)sK[cur];
    const char* sVc = (const char*)sV[cur];
    bf16x8 pf0[4], pf1[4];

#pragma unroll
    for (int grp = 0; grp < 2; grp++) {
      const bf16x8* qf = grp ? qf1 : qf0;
      float& m_r = grp ? m1 : m0;
      float& l_r = grp ? l1 : l0;
      bf16x8* pf = grp ? pf1 : pf0;
      int qg = qw + grp * 32 + l31;
      // --- S^T = K.Q^T ---
      f32x16 sa0 = {}, sa1 = {};
      __builtin_amdgcn_s_setprio(1);
#pragma unroll
      for (int dc = 0; dc < 8; dc++) {
        int cb = (dc * 32 + hi * 16) ^ ((l31 & 7) << 4);
        bf16x8 kf0 = *(const bf16x8*)(sKc + l31 * 256 + cb);
        bf16x8 kf1 = *(const bf16x8*)(sKc + (32 + l31) * 256 + cb);
        sa0 = MFMA32(kf0, qf[dc], sa0, 0, 0, 0);
        sa1 = MFMA32(kf1, qf[dc], sa1, 0, 0, 0);
      }
      __builtin_amdgcn_s_setprio(0);
      // --- raw scores; mask only on diagonal tile ---
      float p[2][16];
      if (!diag) {
#pragma unroll
        for (int r = 0; r < 16; r++) { p[0][r] = sa0[r]; p[1][r] = sa1[r]; }
      } else {
#pragma unroll
        for (int nf = 0; nf < 2; nf++)
#pragma unroll
          for (int r = 0; r < 16; r++) {
            int kg = k0 + nf * 32 + (r & 3) + 8 * (r >> 2) + 4 * hi;
            p[nf][r] = (kg <= qg) ? (nf ? sa1[r] : sa0[r]) : -INFINITY;
          }
      }
      // --- tree max (raw), scale once ---
      float mx[16];
#pragma unroll
      for (int r = 0; r < 16; r++) mx[r] = fmaxf(p[0][r], p[1][r]);
#pragma unroll
      for (int s = 8; s >= 1; s >>= 1)
#pragma unroll
        for (int r = 0; r < 8; r++)
          if (r < s) mx[r] = fmaxf(mx[r], mx[r + s]);
      float pm = mx[0] * SC;
      pm = fmaxf(pm, __shfl_xor(pm, 32));
      bool skip = __all(pm <= m_r + 8.f);  // defer-max (T13)
      float mn = skip ? m_r : fmaxf(m_r, pm);
      float alpha = skip ? 1.f : exp2f(m_r - mn);
      m_r = mn;
      float nm = -m_r;
      // --- exp (SC folded via fma) + tree sum ---
#pragma unroll
      for (int nf = 0; nf < 2; nf++)
#pragma unroll
        for (int r = 0; r < 16; r++)
          p[nf][r] = exp2f(fmaf(p[nf][r], SC, nm));
      float sm[16];
#pragma unroll
      for (int r = 0; r < 16; r++) sm[r] = p[0][r] + p[1][r];
#pragma unroll
      for (int s = 8; s >= 1; s >>= 1)
#pragma unroll
        for (int r = 0; r < 8; r++)
          if (r < s) sm[r] += sm[r + s];
      float rs = sm[0] + __shfl_xor(sm[0], 32);
      l_r = l_r * alpha + rs;
      if (!skip) {
#pragma unroll
        for (int c = 0; c < 4; c++)
#pragma unroll
          for (int r = 0; r < 16; r++) oT[grp * 4 + c][r] *= alpha;
      }
      // --- pack P to bf16 pairs + shfl_xor(32) -> PV A-fragments ---
#pragma unroll
      for (int nf = 0; nf < 2; nf++) {
        u32 Qk[4][2];
#pragma unroll
        for (int gg = 0; gg < 4; gg++) {
          Qk[gg][0] = pkbf(p[nf][4 * gg + 0], p[nf][4 * gg + 1]);
          Qk[gg][1] = pkbf(p[nf][4 * gg + 2], p[nf][4 * gg + 3]);
        }
#pragma unroll
        for (int kc = 0; kc < 2; kc++) {
          u32 x0 = __shfl_xor(Qk[2 * kc + 1 - hi][0], 32);
          u32 x1 = __shfl_xor(Qk[2 * kc + 1 - hi][1], 32);
          u32 o0 = Qk[2 * kc + hi][0], o1 = Qk[2 * kc + hi][1];
          union { u32 w[4]; bf16x8 v; } pv;
          pv.w[0] = hi ? x0 : o0;
          pv.w[1] = hi ? x1 : o1;
          pv.w[2] = hi ? o0 : x0;
          pv.w[3] = hi ? o1 : x1;
          pf[nf * 2 + kc] = pv.v;
        }
      }
    }
    // --- PV: O^T += V^T P^T, V fragments shared by both groups ---
    __builtin_amdgcn_s_setprio(1);
#pragma unroll
    for (int slot = 0; slot < 4; slot++) {
      int vb = (slot * 32 + hi * 16) ^ ((l31 & 7) << 4);
#pragma unroll
      for (int c = 0; c < 4; c++) {
        bf16x8 vf = *(const bf16x8*)(sVc + (c * 32 + l31) * 128 + vb);
        oT[c] = MFMA32(vf, pf0[slot], oT[c], 0, 0, 0);
        oT[4 + c] = MFMA32(vf, pf1[slot], oT[4 + c], 0, 0, 0);
      }
    }
    __builtin_amdgcn_s_setprio(0);
  }
  // --- epilogue ---
  float inv0 = 1.f / l0, inv1 = 1.f / l1;
  size_t row0 = (size_t)b * 2048 + qw + l31;
#pragma unroll
  for (int c = 0; c < 4; c++)
#pragma unroll
    for (int rr = 0; rr < 4; rr++) {
      bf16x4 o4, o5;
#pragma unroll
      for (int j = 0; j < 4; j++) {
        o4[j] = (bf16_t)(oT[c][rr * 4 + j] * inv0);
        o5[j] = (bf16_t)(oT[4 + c][rr * 4 + j] * inv1);
      }
      size_t coloff = h * 128 + c * 32 + rr * 8 + hi * 4;
      *(bf16x4*)(out + row0 * 2048 + coloff) = o4;
      *(bf16x4*)(out + (row0 + 32) * 2048 + coloff) = o5;
    }
}

extern "C" void kernel_launch(void* const* d_in, const int* in_sizes, int n_in,
                              void* d_out, int out_size, void* d_ws, size_t ws_size,
                              hipStream_t stream) {
  const float* x = (const float*)d_in[0];
  const float* Wq = (const float*)d_in[1];
  const float* Wk = (const float*)d_in[2];
  const float* Wv = (const float*)d_in[3];
  const float* Wp = (const float*)d_in[4];
  const float* bp = (const float*)d_in[5];
  float* out = (float*)d_out;

  bf16_t* ws = (bf16_t*)d_ws;
  bf16_t* xb = ws;                          // 8192x2048 (attn out aliases this)
  bf16_t* qkv = ws + 16777216;              // 8192x3072
  bf16_t* WqkvT = ws + 16777216 + 25165824; // 3072x2048 (dead after GEMM1)
  bf16_t* WpT = WqkvT + 6291456;            // 2048x2048
  bf16_t* VT = WqkvT;                       // 2048x2048 VT aliases dead WqkvT

  k_f32_to_bf16<<<2048, 256, 0, stream>>>(x, xb, 16777216L);
  k_transpose_bf16<<<dim3(64, 64), 256, 0, stream>>>(Wq, WqkvT, 2048, 2048);
  k_transpose_bf16<<<dim3(16, 64), 256, 0, stream>>>(Wk, WqkvT + (size_t)2048 * 2048, 2048, 512);
  k_transpose_bf16<<<dim3(16, 64), 256, 0, stream>>>(Wv, WqkvT + (size_t)2560 * 2048, 2048, 512);
  k_transpose_bf16<<<dim3(64, 64), 256, 0, stream>>>(Wp, WpT, 2048, 2048);

  k_gemm_bt<false><<<384, 512, 0, stream>>>(xb, WqkvT, qkv, nullptr, nullptr, 8192, 3072, 2048, 384);
  k_rope<<<40960, 256, 0, stream>>>(qkv);
  k_build_vt<<<dim3(64, 16, 4), 256, 0, stream>>>(qkv, VT);
  k_attn<<<512, 256, 0, stream>>>(qkv, VT, xb);
  k_gemm_bt<true><<<256, 512, 0, stream>>>(xb, WpT, nullptr, out, bp, 8192, 2048, 2048, 256);
}

// Round 9
// 411.033 us; speedup vs baseline: 1.3108x; 1.3108x over previous
//
#include <hip/hip_runtime.h>
#include <hip/hip_bf16.h>
#include <math.h>

typedef __bf16 bf16_t;
typedef __bf16 bf16x8 __attribute__((ext_vector_type(8)));
typedef __bf16 bf16x4 __attribute__((ext_vector_type(4)));
typedef float f32x4 __attribute__((ext_vector_type(4)));
typedef float f32x16 __attribute__((ext_vector_type(16)));
typedef unsigned int u32;

#define MFMA16 __builtin_amdgcn_mfma_f32_16x16x32_bf16
#define MFMA32 __builtin_amdgcn_mfma_f32_32x32x16_bf16

static __device__ __forceinline__ u32 pkbf(float a, float b) {
  union { bf16_t h[2]; u32 u; } z;
  z.h[0] = (bf16_t)a; z.h[1] = (bf16_t)b;
  return z.u;
}

// async global->LDS, 16B per lane, dest = wave-uniform base + lane*16
static __device__ __forceinline__ void gload16(const bf16_t* g, bf16_t* l) {
  __builtin_amdgcn_global_load_lds(
      (const __attribute__((address_space(1))) void*)g,
      (__attribute__((address_space(3))) void*)l, 16, 0, 0);
}

// ---------------- x: f32 -> bf16 ----------------
__global__ void k_f32_to_bf16(const float* __restrict__ in, bf16_t* __restrict__ out, long n) {
  long i = ((long)blockIdx.x * blockDim.x + threadIdx.x) * 4;
  long stride = (long)gridDim.x * blockDim.x * 4;
  for (; i < n; i += stride) {
    const float4 v = *(const float4*)(in + i);
    bf16x4 o; o[0] = (bf16_t)v.x; o[1] = (bf16_t)v.y; o[2] = (bf16_t)v.z; o[3] = (bf16_t)v.w;
    *(bf16x4*)(out + i) = o;
  }
}

// ------------- W (KxN f32) -> WT (NxK bf16), LDS tile transpose -------------
__global__ void k_transpose_bf16(const float* __restrict__ W, bf16_t* __restrict__ WT,
                                 int K, int N) {
  __shared__ float tile[32][33];
  int n0 = blockIdx.x * 32, k0 = blockIdx.y * 32;
  int tx = threadIdx.x & 31, ty = threadIdx.x >> 5;
#pragma unroll
  for (int i = 0; i < 4; i++)
    tile[ty + i * 8][tx] = W[(size_t)(k0 + ty + i * 8) * N + n0 + tx];
  __syncthreads();
#pragma unroll
  for (int i = 0; i < 4; i++) {
    int n = ty + i * 8;
    WT[(size_t)(n0 + n) * K + k0 + tx] = (bf16_t)tile[tx][n];
  }
}

// ------------- V slab of qkv -> VT [b*512 + kvh*128 + d][2048 t] -------------
__global__ void k_build_vt(const bf16_t* __restrict__ qkv, bf16_t* __restrict__ VT) {
  __shared__ bf16_t tile[32][33];
  int t0 = blockIdx.x * 32, c0 = blockIdx.y * 32, b = blockIdx.z;
  int tx = threadIdx.x & 31, ty = threadIdx.x >> 5;
  const bf16_t* src = qkv + (size_t)b * 2048 * 3072 + 2560;
#pragma unroll
  for (int i = 0; i < 4; i++)
    tile[ty + i * 8][tx] = src[(size_t)(t0 + ty + i * 8) * 3072 + c0 + tx];
  __syncthreads();
  bf16_t* dst = VT + (size_t)b * 512 * 2048;
#pragma unroll
  for (int i = 0; i < 4; i++)
    dst[(size_t)(c0 + ty + i * 8) * 2048 + t0 + tx] = tile[tx][ty + i * 8];
}

// ---------------- RoPE on q,k columns of qkv (in place) ----------------
__global__ void k_rope(bf16_t* __restrict__ qkv) {
  int idx = blockIdx.x * blockDim.x + threadIdx.x;
  if (idx >= 8192 * 1280) return;
  int r = idx / 1280, p = idx - r * 1280;
  int t = r & 2047;
  int i = p & 63;
  float theta = exp2f(-(float)i * 0.41524101186092029f);
  float f = (float)t * theta;
  float s, c;
  sincosf(f, &s, &c);
  bf16_t* a = qkv + (size_t)r * 3072 + p * 2;
  float e = (float)a[0], o = (float)a[1];
  a[0] = (bf16_t)(e * c - o * s);
  a[1] = (bf16_t)(e * s + o * c);
}

// ---------------- GEMM v2: 256x256 tile, 8-wave, 4-phase/K-tile pipeline ----
template <bool F32OUT>
__global__ __launch_bounds__(512, 2) void k_gemm_bt(
    const bf16_t* __restrict__ A, const bf16_t* __restrict__ BT,
    bf16_t* __restrict__ Cb, float* __restrict__ Cf,
    const float* __restrict__ bias, int M, int N, int K, int nwg) {
  __shared__ bf16_t smem[65536];  // [2 buf][A 16384 | B 16384]
  const int nbn = N >> 8;
  int orig = (int)blockIdx.x;
  int swz = (orig & 7) * (nwg >> 3) + (orig >> 3);  // bijective, nwg%8==0
  int bm = swz / nbn, bn = swz % nbn;
  const int tid = threadIdx.x;
  const int lane = tid & 63, wid = tid >> 6;
  const int wm = (wid >> 2) << 7;  // 0 / 128
  const int wn = (wid & 3) << 6;   // 0 / 64 / 128 / 192
  const int lr = lane & 15, lq = lane >> 4;
  f32x4 acc[8][4] = {};

  const int rl = tid >> 3;               // row within 64-row chunk
  const int ss = (tid & 7) ^ (rl & 7);   // pre-swizzled source 16B-slot
  const bf16_t* gA = A + (size_t)(bm * 256 + rl) * K + ss * 8;
  const bf16_t* gB = BT + (size_t)(bn * 256 + rl) * K + ss * 8;
  const int lo = wid * 512;  // wave-uniform LDS offset within issue chunk

  const int nt = K >> 6;
  {  // prologue: stage tile 0, full drain once
    bf16_t* sA0 = smem;
    bf16_t* sB0 = smem + 16384;
#pragma unroll
    for (int i = 0; i < 4; i++) {
      gload16(gA + (size_t)i * 64 * K, sA0 + i * 4096 + lo);
      gload16(gB + (size_t)i * 64 * K, sB0 + i * 4096 + lo);
    }
  }
  asm volatile("s_waitcnt vmcnt(0)" ::: "memory");
  __syncthreads();

  for (int t = 0; t < nt; ++t) {
    bf16_t* sAc = smem + (t & 1) * 32768;
    bf16_t* sBc = sAc + 16384;
    bf16_t* sAn = smem + ((t & 1) ^ 1) * 32768;
    bf16_t* sBn = sAn + 16384;
    const int k1 = (t + 1) << 6;
    bf16x8 breg[4][2];
    // ---- phase 0: read all B frags + A frags m0,m1; issue next tile ----
#pragma unroll
    for (int n = 0; n < 4; n++)
#pragma unroll
      for (int kk = 0; kk < 2; kk++) {
        int R = wn + n * 16 + lr;
        int u = (kk * 4 + lq) ^ (R & 7);
        breg[n][kk] = *(const bf16x8*)&sBc[R * 64 + u * 8];
      }
    {
      bf16x8 areg[2][2];
#pragma unroll
      for (int ml = 0; ml < 2; ml++)
#pragma unroll
        for (int kk = 0; kk < 2; kk++) {
          int R = wm + ml * 16 + lr;
          int u = (kk * 4 + lq) ^ (R & 7);
          areg[ml][kk] = *(const bf16x8*)&sAc[R * 64 + u * 8];
        }
      if (t + 1 < nt) {
#pragma unroll
        for (int i = 0; i < 4; i++) {
          gload16(gA + (size_t)i * 64 * K + k1, sAn + i * 4096 + lo);
          gload16(gB + (size_t)i * 64 * K + k1, sBn + i * 4096 + lo);
        }
      }
      __builtin_amdgcn_s_barrier();
      asm volatile("s_waitcnt lgkmcnt(0)" ::: "memory");
      __builtin_amdgcn_sched_barrier(0);
      __builtin_amdgcn_s_setprio(1);
#pragma unroll
      for (int ml = 0; ml < 2; ml++)
#pragma unroll
        for (int n = 0; n < 4; n++)
#pragma unroll
          for (int kk = 0; kk < 2; kk++)
            acc[ml][n] = MFMA16(areg[ml][kk], breg[n][kk], acc[ml][n], 0, 0, 0);
      __builtin_amdgcn_s_setprio(0);
      __builtin_amdgcn_s_barrier();
    }
    // ---- phases 1..3: A frags m=2p..2p+1 ----
#pragma unroll
    for (int p = 1; p < 4; p++) {
      bf16x8 areg[2][2];
#pragma unroll
      for (int ml = 0; ml < 2; ml++)
#pragma unroll
        for (int kk = 0; kk < 2; kk++) {
          int R = wm + (2 * p + ml) * 16 + lr;
          int u = (kk * 4 + lq) ^ (R & 7);
          areg[ml][kk] = *(const bf16x8*)&sAc[R * 64 + u * 8];
        }
      __builtin_amdgcn_s_barrier();
      asm volatile("s_waitcnt lgkmcnt(0)" ::: "memory");
      __builtin_amdgcn_sched_barrier(0);
      __builtin_amdgcn_s_setprio(1);
#pragma unroll
      for (int ml = 0; ml < 2; ml++)
#pragma unroll
        for (int n = 0; n < 4; n++)
#pragma unroll
          for (int kk = 0; kk < 2; kk++)
            acc[2 * p + ml][n] = MFMA16(areg[ml][kk], breg[n][kk], acc[2 * p + ml][n], 0, 0, 0);
      __builtin_amdgcn_s_setprio(0);
      if (p == 3) {
        asm volatile("s_waitcnt vmcnt(0)" ::: "memory");
        __builtin_amdgcn_sched_barrier(0);
      }
      __builtin_amdgcn_s_barrier();
    }
  }
  // ---- epilogue ----
#pragma unroll
  for (int m = 0; m < 8; m++) {
    int row0 = bm * 256 + wm + m * 16 + lq * 4;
#pragma unroll
    for (int n = 0; n < 4; n++) {
      int col = bn * 256 + wn + n * 16 + lr;
#pragma unroll
      for (int r = 0; r < 4; r++) {
        if constexpr (F32OUT)
          Cf[(size_t)(row0 + r) * N + col] = acc[m][n][r] + bias[col];
        else
          Cb[(size_t)(row0 + r) * N + col] = (bf16_t)acc[m][n][r];
      }
    }
  }
}

// ---------------- Flash attention v8 (causal, GQA) ----------------
// 8 waves x 32 q-rows = 256 q-rows/block, 512 thr, grid 512. K/V staged via
// global_load_lds (pre-swizzled source), double-buffered, ONE barrier/tile.
// Per-wave register body identical to the proven round-6 kernel (no spill).
__global__ __launch_bounds__(512, 2) void k_attn(const bf16_t* __restrict__ qkv,
                                                 const bf16_t* __restrict__ VT,
                                                 bf16_t* __restrict__ out) {
  __shared__ bf16_t sK[2][64 * 128];  // [k][d granule-slot^]; slot g holds granule g^(row&7)
  __shared__ bf16_t sV[2][128 * 64];  // [d][k granule-slot^]
  int bid = blockIdx.x;
  int gq = bid >> 6;
  // pair-balanced qt permutation (pairs g, g+4 sum to 7)
  const u32 permbits = (7u) | (5u << 3) | (6u << 6) | (4u << 9) |
                       (0u << 12) | (2u << 15) | (1u << 18) | (3u << 21);
  int qt = (permbits >> (gq * 3)) & 7;
  int bh = bid & 63;
  int h = bh & 15, b = bh >> 4;
  int kvh = h >> 2;
  const size_t RS = 3072;
  const bf16_t* Qb = qkv + (size_t)b * 2048 * RS + h * 128;
  const bf16_t* Kb = qkv + (size_t)b * 2048 * RS + 2048 + kvh * 128;
  const bf16_t* Vt = VT + (size_t)(b * 4 + kvh) * 128 * 2048;
  int tid = threadIdx.x, lane = tid & 63, wid = tid >> 6;
  int l31 = lane & 31, hi = lane >> 5;
  int qw = qt * 256 + wid * 32;  // this wave's 32 q-rows

  // Q fragments (B operand: row=l31, k = dc*16 + hi*8 + j)
  bf16x8 qf[8];
  {
    const bf16_t* qrow = Qb + (size_t)(qw + l31) * RS + hi * 8;
#pragma unroll
    for (int dc = 0; dc < 8; dc++)
      qf[dc] = *(const bf16x8*)(qrow + dc * 16);
  }

  // staging source addresses, pre-swizzled (rule 21: source perm == read perm)
  // K: 64 rows x 256B; thread covers row rl=tid>>4 (+32/issue), granule tid&15
  const int rlk = tid >> 4;
  const bf16_t* Kst = Kb + (size_t)rlk * RS + (size_t)(((tid & 15) ^ (rlk & 7)) * 8);
  // V: 128 rows x 128B; row vd=tid>>3 (+64/issue), granule tid&7
  const int vdr = tid >> 3;
  const bf16_t* Vst = Vt + (size_t)vdr * 2048 + (size_t)(((tid & 7) ^ (vdr & 7)) * 8);
  const int lo = wid * 512;  // wave-uniform LDS elem offset per issue chunk

  f32x16 oT[4] = {};
  float m_r = -INFINITY, l_r = 0.f;
  const float SC = 0.08838834764831845f * 1.4426950408889634f;  // D^-0.5 * log2(e)

  int ntiles = qt * 4 + 4;
  // prologue: stage tile 0 into buf 0
#pragma unroll
  for (int i = 0; i < 2; i++)
    gload16(Kst + (size_t)(i * 32) * RS, &sK[0][i * 4096 + lo]);
#pragma unroll
  for (int i = 0; i < 2; i++)
    gload16(Vst + (size_t)(i * 64) * 2048, &sV[0][i * 4096 + lo]);

  for (int kt = 0; kt < ntiles; kt++) {
    int k0 = kt << 6;
    int cur = kt & 1;
    asm volatile("s_waitcnt vmcnt(0)" ::: "memory");
    __builtin_amdgcn_s_barrier();
    __builtin_amdgcn_sched_barrier(0);
    if (kt + 1 < ntiles) {
      int k1 = k0 + 64;
#pragma unroll
      for (int i = 0; i < 2; i++)
        gload16(Kst + (size_t)(k1 + i * 32) * RS, &sK[cur ^ 1][i * 4096 + lo]);
#pragma unroll
      for (int i = 0; i < 2; i++)
        gload16(Vst + (size_t)(i * 64) * 2048 + k1, &sV[cur ^ 1][i * 4096 + lo]);
    }
    if (k0 > qw) continue;  // wave-uniform causal skip (barrier already passed)
    bool diag = (qw - k0) < 64;
    const char* sKc = (const char*)sK[cur];
    const char* sVc = (const char*)sV[cur];

    // --- S^T = K.Q^T : D[k][q], k=(r&3)+8*(r>>2)+4*hi (+32*nf), q=l31 ---
    f32x16 sa0 = {}, sa1 = {};
    __builtin_amdgcn_s_setprio(1);
#pragma unroll
    for (int dc = 0; dc < 8; dc++) {
      int cb = (dc * 32 + hi * 16) ^ ((l31 & 7) << 4);
      bf16x8 kf0 = *(const bf16x8*)(sKc + l31 * 256 + cb);
      bf16x8 kf1 = *(const bf16x8*)(sKc + (32 + l31) * 256 + cb);
      sa0 = MFMA32(kf0, qf[dc], sa0, 0, 0, 0);
      sa1 = MFMA32(kf1, qf[dc], sa1, 0, 0, 0);
    }
    __builtin_amdgcn_s_setprio(0);
    // --- raw scores; mask only on diagonal tiles ---
    float p[2][16];
    int qg = qw + l31;
    if (!diag) {
#pragma unroll
      for (int r = 0; r < 16; r++) { p[0][r] = sa0[r]; p[1][r] = sa1[r]; }
    } else {
#pragma unroll
      for (int nf = 0; nf < 2; nf++)
#pragma unroll
        for (int r = 0; r < 16; r++) {
          int kg = k0 + nf * 32 + (r & 3) + 8 * (r >> 2) + 4 * hi;
          p[nf][r] = (kg <= qg) ? (nf ? sa1[r] : sa0[r]) : -INFINITY;
        }
    }
    // --- tree max (raw domain), scale once ---
    float mx[16];
#pragma unroll
    for (int r = 0; r < 16; r++) mx[r] = fmaxf(p[0][r], p[1][r]);
#pragma unroll
    for (int s = 8; s >= 1; s >>= 1)
#pragma unroll
      for (int r = 0; r < 8; r++)
        if (r < s) mx[r] = fmaxf(mx[r], mx[r + s]);
    float pm = mx[0] * SC;
    pm = fmaxf(pm, __shfl_xor(pm, 32));
    bool skip = __all(pm <= m_r + 8.f);  // defer-max (T13)
    float mn = skip ? m_r : fmaxf(m_r, pm);
    float alpha = skip ? 1.f : exp2f(m_r - mn);
    m_r = mn;
    float nm = -m_r;
    // --- exp via fma (SC folded) + tree sum ---
#pragma unroll
    for (int nf = 0; nf < 2; nf++)
#pragma unroll
      for (int r = 0; r < 16; r++)
        p[nf][r] = exp2f(fmaf(p[nf][r], SC, nm));
    float sm[16];
#pragma unroll
    for (int r = 0; r < 16; r++) sm[r] = p[0][r] + p[1][r];
#pragma unroll
    for (int s = 8; s >= 1; s >>= 1)
#pragma unroll
      for (int r = 0; r < 8; r++)
        if (r < s) sm[r] += sm[r + s];
    float rs = sm[0] + __shfl_xor(sm[0], 32);
    l_r = l_r * alpha + rs;
    if (!skip) {
#pragma unroll
      for (int c = 0; c < 4; c++)
#pragma unroll
        for (int r = 0; r < 16; r++) oT[c][r] *= alpha;
    }
    // --- P handoff in-register (pack + shfl_xor(32)) + PV: O^T += V^T P^T ---
#pragma unroll
    for (int nf = 0; nf < 2; nf++) {
      u32 Qk[4][2];
#pragma unroll
      for (int gg = 0; gg < 4; gg++) {
        Qk[gg][0] = pkbf(p[nf][4 * gg + 0], p[nf][4 * gg + 1]);
        Qk[gg][1] = pkbf(p[nf][4 * gg + 2], p[nf][4 * gg + 3]);
      }
#pragma unroll
      for (int kc = 0; kc < 2; kc++) {
        u32 x0 = __shfl_xor(Qk[2 * kc + 1 - hi][0], 32);
        u32 x1 = __shfl_xor(Qk[2 * kc + 1 - hi][1], 32);
        u32 o0 = Qk[2 * kc + hi][0], o1 = Qk[2 * kc + hi][1];
        union { u32 w[4]; bf16x8 v; } pf;
        pf.w[0] = hi ? x0 : o0;
        pf.w[1] = hi ? x1 : o1;
        pf.w[2] = hi ? o0 : x0;
        pf.w[3] = hi ? o1 : x1;
        int slot = nf * 2 + kc;
        int vb = (slot * 32 + hi * 16) ^ ((l31 & 7) << 4);
        __builtin_amdgcn_s_setprio(1);
#pragma unroll
        for (int c = 0; c < 4; c++) {
          bf16x8 vf = *(const bf16x8*)(sVc + (c * 32 + l31) * 128 + vb);
          oT[c] = MFMA32(vf, pf.v, oT[c], 0, 0, 0);
        }
        __builtin_amdgcn_s_setprio(0);
      }
    }
  }
  // --- epilogue: O^T store, lane-local l ---
  float inv = 1.f / l_r;
  size_t row = (size_t)b * 2048 + qw + l31;
#pragma unroll
  for (int c = 0; c < 4; c++)
#pragma unroll
    for (int rr = 0; rr < 4; rr++) {
      bf16x4 o4;
#pragma unroll
      for (int j = 0; j < 4; j++) o4[j] = (bf16_t)(oT[c][rr * 4 + j] * inv);
      *(bf16x4*)(out + row * 2048 + h * 128 + c * 32 + rr * 8 + hi * 4) = o4;
    }
}

extern "C" void kernel_launch(void* const* d_in, const int* in_sizes, int n_in,
                              void* d_out, int out_size, void* d_ws, size_t ws_size,
                              hipStream_t stream) {
  const float* x = (const float*)d_in[0];
  const float* Wq = (const float*)d_in[1];
  const float* Wk = (const float*)d_in[2];
  const float* Wv = (const float*)d_in[3];
  const float* Wp = (const float*)d_in[4];
  const float* bp = (const float*)d_in[5];
  float* out = (float*)d_out;

  bf16_t* ws = (bf16_t*)d_ws;
  bf16_t* xb = ws;                          // 8192x2048 (attn out aliases this)
  bf16_t* qkv = ws + 16777216;              // 8192x3072
  bf16_t* WqkvT = ws + 16777216 + 25165824; // 3072x2048 (dead after GEMM1)
  bf16_t* WpT = WqkvT + 6291456;            // 2048x2048
  bf16_t* VT = WqkvT;                       // 2048x2048 VT aliases dead WqkvT

  k_f32_to_bf16<<<2048, 256, 0, stream>>>(x, xb, 16777216L);
  k_transpose_bf16<<<dim3(64, 64), 256, 0, stream>>>(Wq, WqkvT, 2048, 2048);
  k_transpose_bf16<<<dim3(16, 64), 256, 0, stream>>>(Wk, WqkvT + (size_t)2048 * 2048, 2048, 512);
  k_transpose_bf16<<<dim3(16, 64), 256, 0, stream>>>(Wv, WqkvT + (size_t)2560 * 2048, 2048, 512);
  k_transpose_bf16<<<dim3(64, 64), 256, 0, stream>>>(Wp, WpT, 2048, 2048);

  k_gemm_bt<false><<<384, 512, 0, stream>>>(xb, WqkvT, qkv, nullptr, nullptr, 8192, 3072, 2048, 384);
  k_rope<<<40960, 256, 0, stream>>>(qkv);
  k_build_vt<<<dim3(64, 16, 4), 256, 0, stream>>>(qkv, VT);
  k_attn<<<512, 512, 0, stream>>>(qkv, VT, xb);
  k_gemm_bt<true><<<256, 512, 0, stream>>>(xb, WpT, nullptr, out, bp, 8192, 2048, 2048, 256);
}